// Round 9
// baseline (112.901 us; speedup 1.0000x reference)
//
#include <hip/hip_runtime.h>

#define RADIUS 8
#define N 512
#define TR 32                   // rows per strip
#define SPB 2                   // strips per block, register-carried halo
#define LSTRIDE 516             // dwords; %4==0 → 16B-aligned rows for ds_read_b128

__global__ __launch_bounds__(512, 4)
void box_kernel(const float* __restrict__ in, float* __restrict__ out) {
    __shared__ __align__(16) float tile[TR * LSTRIDE];   // 66,048 B → 2 blocks/CU

    const int blk   = blockIdx.x;
    const int img   = blk >> 3;            // 8 groups of 64 rows per image
    const int grp   = blk & 7;
    const int rbase = grp * (TR * SPB);
    const float* __restrict__ ibase = in  + (size_t)img * N * N;
    float* __restrict__       obase = out + (size_t)img * N * N;
    const int t = threadIdx.x;
    const int c = t;                       // phase-1 column

    // Strip-0 window burst: rows [rbase-8, rbase+40) — 48 independent loads.
    float x[48];
#pragma unroll
    for (int k = 0; k < 48; ++k) {
        const int row = rbase + k - RADIUS;
        x[k] = (row >= 0 && row < N) ? ibase[(size_t)row * N + c] : 0.0f;
    }

    const int qid  = t & 127;              // phase-2: col-quad 0..127
    const int rgrp = t >> 7;               // phase-2: row-group 0..3
    const int q0   = qid * 4;

#pragma unroll
    for (int s = 0; s < SPB; ++s) {
        const int r0 = rbase + s * TR;

        // ---- Phase 1: vertical 17-tap sliding sum from registers → LDS.
        {
            float vs = 0.0f;
#pragma unroll
            for (int k = 0; k <= 2 * RADIUS; ++k) vs += x[k];
#pragma unroll
            for (int i = 0; i < TR; ++i) {
                tile[i * LSTRIDE + c] = vs;
                if (i + 1 < TR) vs += x[i + 2 * RADIUS + 1] - x[i];
            }
        }

        // ---- Carry halo + issue next strip's 32 fresh loads BEFORE the
        // barrier: latency hides under barrier-wait + phase 2.
        if (s + 1 < SPB) {
#pragma unroll
            for (int k = 0; k < 16; ++k) x[k] = x[32 + k];   // rows [r0+24, r0+40)
#pragma unroll
            for (int k = 0; k < 32; ++k) {
                const int row = r0 + TR + RADIUS + k;        // [r0+40, r0+72), ≥0
                x[16 + k] = (row < N) ? ibase[(size_t)row * N + c] : 0.0f;
            }
        }
        __syncthreads();

        // ---- Phase 2: horizontal 17-tap sum; 5 aligned ds_read_b128 per row;
        // wave = 64 consecutive quads on ONE row → 1 KB contiguous stores.
#pragma unroll
        for (int i = 0; i < 8; ++i) {
            const int r = rgrp * 8 + i;
            const float* trow = &tile[r * LSTRIDE];
            float wv[20];                  // window cols q0-8 .. q0+11 (OOB → 0)
#pragma unroll
            for (int p = 0; p < 5; ++p) {
                const int cs = q0 - 8 + 4 * p;               // ≡ 0 mod 4
                float4 vv = (cs >= 0 && cs < N)
                          ? *reinterpret_cast<const float4*>(trow + cs)
                          : make_float4(0.0f, 0.0f, 0.0f, 0.0f);
                wv[4 * p + 0] = vv.x; wv[4 * p + 1] = vv.y;
                wv[4 * p + 2] = vv.z; wv[4 * p + 3] = vv.w;
            }
            float sum = 0.0f;
#pragma unroll
            for (int k = 0; k < 17; ++k) sum += wv[k];
            const float o0 = sum;
            const float o1 = o0 - wv[0] + wv[17];
            const float o2 = o1 - wv[1] + wv[18];
            const float o3 = o2 - wv[2] + wv[19];
            *reinterpret_cast<float4*>(obase + (size_t)(r0 + r) * N + q0) =
                make_float4(o0, o1, o2, o3);
        }

        if (s + 1 < SPB) __syncthreads();  // P2 reads done before next P1 overwrite
    }
}

extern "C" void kernel_launch(void* const* d_in, const int* in_sizes, int n_in,
                              void* d_out, int out_size, void* d_ws, size_t ws_size,
                              hipStream_t stream) {
    const float* in = (const float*)d_in[0];
    float* out = (float*)d_out;
    dim3 grid(8 * 32 * (N / (TR * SPB)));  // 2048 blocks = 4 rounds of turnover
    dim3 block(512);
    hipLaunchKernelGGL(box_kernel, grid, block, 0, stream, in, out);
}

// Round 10
// 109.416 us; speedup vs baseline: 1.0319x; 1.0319x over previous
//
#include <hip/hip_runtime.h>

#define RADIUS 8
#define N 512
#define TR 32                 // output rows per block strip
#define LSTRIDE (N + 1)       // LDS row stride: 513 ≡ 1 (mod 32 banks) → conflict-free

__global__ __launch_bounds__(512, 4)
void box_kernel(const float* __restrict__ in, float* __restrict__ out) {
    __shared__ float tile[TR * LSTRIDE];   // 32 * 513 * 4 B = 64.1 KiB

    const int blk   = blockIdx.x;
    const int img   = blk >> 4;            // 16 strips per 512-row image
    const int strip = blk & 15;
    const int r0    = strip * TR;
    const float* __restrict__ ibase = in  + (size_t)img * N * N;
    float* __restrict__       obase = out + (size_t)img * N * N;
    const int c = threadIdx.x;             // column 0..511

    // ---- Phase 1: vertical zero-padded 17-tap sliding sum, column c ----
    // Burst-load ALL 48 window rows first: 48 independent outstanding loads
    // per wave is the MLP that saturates the request pipe (10.1 B/cy/CU).
    float x[TR + 2 * RADIUS];
#pragma unroll
    for (int k = 0; k < TR + 2 * RADIUS; ++k) {
        const int row = r0 + k - RADIUS;
        x[k] = (row >= 0 && row < N) ? ibase[(size_t)row * N + c] : 0.0f;
    }
    float vs = 0.0f;
#pragma unroll
    for (int k = 0; k <= 2 * RADIUS; ++k) vs += x[k];   // window for output row r0
#pragma unroll
    for (int i = 0; i < TR; ++i) {
        tile[i * LSTRIDE + c] = vs;                     // banks (i + c) % 32 → 2-way, free
        if (i + 1 < TR) vs += x[i + 2 * RADIUS + 1] - x[i];
    }
    __syncthreads();

    // ---- Phase 2: horizontal zero-padded 17-tap sliding sum within tile rows ----
    const int hrow = threadIdx.x & (TR - 1);   // 0..31
    const int seg  = threadIdx.x >> 5;         // 0..15, 32 cols each
    const int c0   = seg * 32;
    const float* trow = &tile[hrow * LSTRIDE];
    float h[32];
    float hs = 0.0f;
#pragma unroll
    for (int k = -RADIUS; k <= RADIUS; ++k) {  // initial window for col c0
        const int col = c0 + k;
        if (col >= 0 && col < N) hs += trow[col];
    }
#pragma unroll
    for (int j = 0; j < 32; ++j) {
        h[j] = hs;
        const int ac = c0 + j + 1 + RADIUS;
        const int sc = c0 + j - RADIUS;
        const float a = (ac < N) ? trow[ac] : 0.0f;
        const float s = (sc >= 0) ? trow[sc] : 0.0f;
        hs += a - s;
    }
    __syncthreads();

    // write results back into the tile (in-place is safe: all reads completed)
    float* twrow = &tile[hrow * LSTRIDE];
#pragma unroll
    for (int j = 0; j < 32; ++j) twrow[c0 + j] = h[j];
    __syncthreads();

    // ---- Phase 3: coalesced store (2 KiB contiguous per row) ----
#pragma unroll
    for (int i = 0; i < TR; ++i) {
        obase[(size_t)(r0 + i) * N + c] = tile[i * LSTRIDE + c];
    }
}

extern "C" void kernel_launch(void* const* d_in, const int* in_sizes, int n_in,
                              void* d_out, int out_size, void* d_ws, size_t ws_size,
                              hipStream_t stream) {
    const float* in = (const float*)d_in[0];
    float* out = (float*)d_out;
    const int images = 8 * 32;                 // batch * channels
    dim3 grid(images * (N / TR));              // 4096 blocks
    dim3 block(512);
    hipLaunchKernelGGL(box_kernel, grid, block, 0, stream, in, out);
}